// Round 1
// baseline (49.220 us; speedup 1.0000x reference)
//
#include <hip/hip_runtime.h>

// DynamicFiltering: out[b,c,y,x] = sum_{ki,kj} padded_img[b,c,y+ki,x+kj] * kernels[b,c,ki*3+kj,y,x]
// img: [B,C,H,W] f32; kernels: [B,C,9,H,W] f32; out: [B,C,H,W] f32. pad=1 (zeros).
// Memory-bound: kernels tensor (226.5 MB) dominates. Strategy: float4 along W,
// one thread = 4 output pixels, all loads coalesced.

#define KSZ 3

__global__ __launch_bounds__(256) void dynfilt_kernel(
    const float* __restrict__ img,
    const float* __restrict__ kern,
    float* __restrict__ out,
    int B, int C, int H, int W)
{
    const int W4 = W >> 2;                       // float4 groups per row
    const int tid = blockIdx.x * blockDim.x + threadIdx.x;
    const int total = B * C * H * W4;
    if (tid >= total) return;

    const int x4 = tid % W4;
    const int y  = (tid / W4) % H;
    const int bc = tid / (W4 * H);               // b*C + c
    const int x0 = x4 << 2;

    const size_t plane = (size_t)H * W;
    const float* imgp  = img  + (size_t)bc * plane;
    const float* kernp = kern + (size_t)bc * 9 * plane + (size_t)y * W + x0;

    // Load 3x6 image window (rows y-1..y+1, cols x0-1..x0+4), zero-padded.
    float win[3][6];
    #pragma unroll
    for (int ki = 0; ki < 3; ++ki) {
        const int yy = y + ki - 1;
        if (yy < 0 || yy >= H) {
            #pragma unroll
            for (int j = 0; j < 6; ++j) win[ki][j] = 0.0f;
        } else {
            const float* rowp = imgp + (size_t)yy * W + x0;
            const float4 v = *reinterpret_cast<const float4*>(rowp);
            win[ki][1] = v.x; win[ki][2] = v.y; win[ki][3] = v.z; win[ki][4] = v.w;
            win[ki][0] = (x0 > 0)      ? rowp[-1] : 0.0f;
            win[ki][5] = (x0 + 4 < W)  ? rowp[4]  : 0.0f;
        }
    }

    float4 acc = make_float4(0.f, 0.f, 0.f, 0.f);
    #pragma unroll
    for (int ki = 0; ki < 3; ++ki) {
        #pragma unroll
        for (int kj = 0; kj < 3; ++kj) {
            const int kk = ki * 3 + kj;
            const float4 kv = *reinterpret_cast<const float4*>(kernp + (size_t)kk * plane);
            acc.x = fmaf(win[ki][0 + kj], kv.x, acc.x);
            acc.y = fmaf(win[ki][1 + kj], kv.y, acc.y);
            acc.z = fmaf(win[ki][2 + kj], kv.z, acc.z);
            acc.w = fmaf(win[ki][3 + kj], kv.w, acc.w);
        }
    }

    *reinterpret_cast<float4*>(out + (size_t)bc * plane + (size_t)y * W + x0) = acc;
}

extern "C" void kernel_launch(void* const* d_in, const int* in_sizes, int n_in,
                              void* d_out, int out_size, void* d_ws, size_t ws_size,
                              hipStream_t stream)
{
    const float* img  = (const float*)d_in[0];
    const float* kern = (const float*)d_in[1];
    float* out = (float*)d_out;

    const int B = 8, C = 3, H = 512, W = 512;
    const int total = B * C * H * (W >> 2);
    const int block = 256;
    const int grid = (total + block - 1) / block;
    dynfilt_kernel<<<grid, block, 0, stream>>>(img, kern, out, B, C, H, W);
}